// Round 7
// baseline (151.986 us; speedup 1.0000x reference)
//
#include <hip/hip_runtime.h>
#include <hip/hip_bf16.h>

// RoI crop: out[n,b,i,j,c] = features[b, x1(n)+i, y1(n)+j, c]
// features: [B=8, 64, 64, C=256] f32 ; boxes: [N=1000, 4] i32 (x1,y1,x2,y2)
// out: [N, B, 7, 7, C] f32  (401 MB streaming write)
//
// R6: swap the cache roles. R3/R5 (nt stores) plateau at ~5 TB/s write;
// harness fill proves 6.9 TB/s via the L2 write-back path (plain stores).
// R4 (plain stores + L2-cached reads) thrashed the exactly-4MB feature
// slice. So: NT LOADS (reads served by 256MB L3, don't pollute L2) +
// PLAIN STORES (write-allocate full 1KB-contiguous lines, write-back
// streams at fill's rate). L2 becomes a pure write buffer.
//  - R5's 1-row double-buffer pipeline kept (compile-time indices).
//  - 2000 blocks x 4 waves; wave = one (n,b): 49 rows x 1 KB contiguous.

#define ANCHOR 7
#define FS     64
#define NBOX   1000
#define BB     8
#define CC     256
#define C4     (CC / 4)                 // 64 f32x4 per row
#define ROWS   (BB * ANCHOR * ANCHOR)   // 392 rows per box

typedef float f32x4 __attribute__((ext_vector_type(4)));

__global__ __launch_bounds__(256) void roi_crop_kernel(
    const f32x4* __restrict__ fin,      // features as f32x4
    const int*   __restrict__ boxes,    // [N,4]
    f32x4*       __restrict__ fout)     // out as f32x4
{
    const int lane = threadIdx.x & 63;
    const int wave = threadIdx.x >> 6;          // 0..3
    const int x    = blockIdx.x;                // 0..1999
    const int b    = x & 7;                     // batch slice
    const int n    = (x >> 3) * 4 + wave;       // box index, 0..999

    int x1 = boxes[n * 4 + 0];
    int y1 = boxes[n * 4 + 1];
    x1 = min(max(x1, 0), FS - ANCHOR);
    y1 = min(max(y1, 0), FS - ANCHOR);

    const f32x4* __restrict__ src = fin + ((b * FS + x1) * FS + y1) * C4 + lane;
    f32x4* __restrict__ dst = fout + n * (ROWS * C4) + b * (ANCHOR * ANCHOR * C4) + lane;

    f32x4 buf[2][ANCHOR];

    // prologue: load row 0 (non-temporal: bypass/evict-first in L2)
    #pragma unroll
    for (int j = 0; j < ANCHOR; ++j)
        buf[0][j] = __builtin_nontemporal_load(&src[j * C4]);

    #pragma unroll
    for (int i = 0; i < ANCHOR; ++i) {
        if (i + 1 < ANCHOR) {               // load row i+1 first (next buffer)
            #pragma unroll
            for (int j = 0; j < ANCHOR; ++j)
                buf[(i + 1) & 1][j] =
                    __builtin_nontemporal_load(&src[((i + 1) * FS + j) * C4]);
        }
        #pragma unroll
        for (int j = 0; j < ANCHOR; ++j)    // plain stores: L2 write-back path
            dst[(i * ANCHOR + j) * C4] = buf[i & 1][j];
    }
}

extern "C" void kernel_launch(void* const* d_in, const int* in_sizes, int n_in,
                              void* d_out, int out_size, void* d_ws, size_t ws_size,
                              hipStream_t stream) {
    const f32x4* fin  = (const f32x4*)d_in[0];
    const int*  boxes = (const int*)d_in[1];
    f32x4*      fout  = (f32x4*)d_out;

    roi_crop_kernel<<<NBOX * BB / 4, 256, 0, stream>>>(fin, boxes, fout);
}

// Round 8
// 77.930 us; speedup vs baseline: 1.9503x; 1.9503x over previous
//
#include <hip/hip_runtime.h>
#include <hip/hip_bf16.h>

// RoI crop: out[n,b,i,j,c] = features[b, x1(n)+i, y1(n)+j, c]
// features: [B=8, 64, 64, C=256] f32 ; boxes: [N=1000, 4] i32 (x1,y1,x2,y2)
// out: [N, B, 7, 7, C] f32  (401 MB streaming write)
//
// R7: fire-and-forget waves to break the FIFO-vmcnt store coupling.
// vmcnt is a single in-order counter for loads AND stores; any load-wait
// emitted after stores (R3/R5 inner loops) transitively waits for nt-store
// COMPLETION (~600-900cy HBM ack) -> ~5 TB/s plateau. Here each wave:
//   issue ALL its loads -> one vmcnt wait (queue holds loads only)
//   -> issue ALL its nt stores -> s_endpgm (stores drain post-retirement).
// No load ever queues behind a store inside a wave.
//  - Kept from R3/R5: XCD-pinned reads (b = blockIdx&7 -> 4MB slice per
//    XCD L2), nt stores (R4/R6 proved plain stores thrash the pinned slice).
//  - Block = one (n,b) plane; 4 waves take rows [13,12,12,12] of 49.

#define ANCHOR 7
#define FS     64
#define NBOX   1000
#define BB     8
#define CC     256
#define C4     (CC / 4)                 // 64 f32x4 per 1KB row
#define ROWS   (BB * ANCHOR * ANCHOR)   // 392 rows per box
#define MAXR   13

typedef float f32x4 __attribute__((ext_vector_type(4)));

__global__ __launch_bounds__(256) void roi_crop_kernel(
    const f32x4* __restrict__ fin,      // features as f32x4
    const int*   __restrict__ boxes,    // [N,4]
    f32x4*       __restrict__ fout)     // out as f32x4
{
    const int lane = threadIdx.x & 63;
    const int wave = threadIdx.x >> 6;          // 0..3
    const int x    = blockIdx.x;                // 0..7999
    const int b    = x & 7;                     // batch slice == XCD id
    const int n    = x >> 3;                    // box index, 0..999

    int x1 = boxes[n * 4 + 0];
    int y1 = boxes[n * 4 + 1];
    x1 = min(max(x1, 0), FS - ANCHOR);
    y1 = min(max(y1, 0), FS - ANCHOR);

    // rows [start, start+cnt) of the 49-row (n,b) plane; wave-uniform
    const int start = (wave == 0) ? 0 : 1 + 12 * wave;   // 0,13,25,37
    const int cnt   = (wave == 0) ? 13 : 12;

    const f32x4* __restrict__ src = fin + ((b * FS + x1) * FS + y1) * C4 + lane;
    f32x4* __restrict__ dst = fout + n * (ROWS * C4) + b * (ANCHOR * ANCHOR * C4)
                              + start * C4 + lane;

    f32x4 buf[MAXR];

    // phase 1: issue ALL loads (vmcnt queue = loads only)
    #pragma unroll
    for (int t = 0; t < MAXR; ++t) {
        if (t < cnt) {                       // wave-uniform branch
            int r = start + t;
            int i = r / ANCHOR;
            int j = r - i * ANCHOR;
            buf[t] = src[(i * FS + j) * C4];
        }
    }

    // phase 2: one implicit vmcnt wait, then ALL nt stores; wave retires
    // with stores in flight (never waited on).
    #pragma unroll
    for (int t = 0; t < MAXR; ++t) {
        if (t < cnt)
            __builtin_nontemporal_store(buf[t], &dst[t * C4]);
    }
}

extern "C" void kernel_launch(void* const* d_in, const int* in_sizes, int n_in,
                              void* d_out, int out_size, void* d_ws, size_t ws_size,
                              hipStream_t stream) {
    const f32x4* fin  = (const f32x4*)d_in[0];
    const int*  boxes = (const int*)d_in[1];
    f32x4*      fout  = (f32x4*)d_out;

    roi_crop_kernel<<<NBOX * BB, 256, 0, stream>>>(fin, boxes, fout);
}